// Round 10
// baseline (1096.269 us; speedup 1.0000x reference)
//
#include <hip/hip_runtime.h>
#include <stdint.h>

typedef __attribute__((ext_vector_type(4))) float  float4v;
typedef __attribute__((ext_vector_type(8))) __bf16 bf16x8;
typedef __attribute__((ext_vector_type(8))) unsigned short ushort8;

#define B_DIM 8192
#define H_DIM 1024
#define O_DIM 1024

static __device__ __forceinline__ unsigned short f32_to_bf16(float f) {
  union { float f; unsigned int u; } v; v.f = f;
  unsigned int u = v.u;
  unsigned int r = u + 0x7FFFu + ((u >> 16) & 1u);  // round-to-nearest-even
  return (unsigned short)(r >> 16);
}

// ---------------------------------------------------------------------------
// prep_inputs: unchanged (near memory floor).
// ---------------------------------------------------------------------------
__global__ void prep_inputs(const float* __restrict__ state,
                            const float* __restrict__ basis,
                            const float* __restrict__ prjw,
                            unsigned short* __restrict__ Abf,
                            unsigned short* __restrict__ Wt) {
  __shared__ __align__(16) unsigned short t[64 * 72];
  int bb = blockIdx.x;
  int tid = threadIdx.x;
  if (bb < 1280) {
    int m = bb >> 8, panel = bb & 255;
    int o0 = (panel & 15) * 64, h0 = (panel >> 4) * 64;
    const float* src = (m < 4) ? (basis + (size_t)m * H_DIM * O_DIM) : prjw;  // [H][O]
    int r  = tid >> 4;
    int c4 = (tid & 15) * 4;
#pragma unroll
    for (int p = 0; p < 4; ++p) {
      int h = r + p * 16;
      float4v v = *(const float4v*)(src + (size_t)(h0 + h) * O_DIM + o0 + c4);
      t[(c4 + 0) * 72 + h] = f32_to_bf16(v.x);
      t[(c4 + 1) * 72 + h] = f32_to_bf16(v.y);
      t[(c4 + 2) * 72 + h] = f32_to_bf16(v.z);
      t[(c4 + 3) * 72 + h] = f32_to_bf16(v.w);
    }
    __syncthreads();
#pragma unroll
    for (int i = 0; i < 2; ++i) {
      int C = i * 256 + tid;
      int o = C >> 3, cc = C & 7;
      ushort8 val = *(const ushort8*)(t + o * 72 + cc * 8);
      *(ushort8*)(Wt + ((size_t)m * O_DIM + o0 + o) * H_DIM + h0 + cc * 8) = val;
    }
  } else {
    int i = (bb - 1280) * 256 + tid;  // 8 elems per thread
    float4v v0 = ((const float4v*)state)[i * 2];
    float4v v1 = ((const float4v*)state)[i * 2 + 1];
    ushort8 o;
    o[0] = f32_to_bf16(v0.x); o[1] = f32_to_bf16(v0.y);
    o[2] = f32_to_bf16(v0.z); o[3] = f32_to_bf16(v0.w);
    o[4] = f32_to_bf16(v1.x); o[5] = f32_to_bf16(v1.y);
    o[6] = f32_to_bf16(v1.z); o[7] = f32_to_bf16(v1.w);
    ((ushort8*)Abf)[i] = o;
  }
}

// ---------------------------------------------------------------------------
// R10: occupancy lever.  R9 (counted 3-ring, 1 barrier) == R4 (drain 2-ring)
//  within 2% -> sync style is not the constraint; 2 waves/SIMD is: all
//  resident waves sit in one barrier group, so read bursts and MFMA stretches
//  coincide and the LDS/matrix pipes serialize (wall ~= sum, 3082 cyc/stage).
//  Fix: ring 3->2 slots (72KB + 5KB scf = 77KB < 80KB) -> 2 blocks/CU ->
//  16 waves/CU = 4 waves/SIMD, two INDEPENDENT barrier groups per CU.
//  2-slot ledger needs 2 barriers/stage (m201 pattern):
//   ISSUE(s+1 -> other slot)  // slot freed by barrier B of stage s-1
//   vmcnt(L)                  // outstanding L(s)+L(s+1) -> wait to L = s landed
//   barrier A                 // ALL waves' DMA(s) landed
//   14 ds_reads (slot s) ; 40 MFMA (compiler-counted lgkmcnt)
//   barrier B                 // all done reading slot s -> free for s+2
//  vmcnt never 0 mid-loop.  Slot layout identical to R9 (verified offsets).
// ---------------------------------------------------------------------------
__global__ __launch_bounds__(512, 4)
void gemm_fused(const unsigned short* __restrict__ A,
                const unsigned short* __restrict__ Wt,
                const float* __restrict__ se, const float* __restrict__ curv,
                const float* __restrict__ gw, const float* __restrict__ gb,
                const float* __restrict__ prjb,
                float* __restrict__ out) {
  __shared__ __align__(16) unsigned char smem[78848];  // 2*36864 + 5120 (scf)
  float* scf = (float*)(smem + 73728);  // 5 x 256 fp32 = 5120 B

  const int tid  = threadIdx.x;
  const int lane = tid & 63;
  const int wave = tid >> 6;
  const int row0 = blockIdx.x * 256;
  const int col0 = blockIdx.y * 64;
  const int wrow = (wave >> 1) * 64;   // 0,64,128,192
  const int wcol = (wave & 1) * 32;    // 0 or 32
  const int q  = lane >> 4;
  const int ln = lane & 15;

  // ---- staging descriptors.  1KB wave-chunk = 16 rows x 32k bf16.
  const unsigned short* gsrc[5];
  unsigned int ldsoff[5];
  if (wave < 4) {
#pragma unroll
    for (int j = 0; j < 4; ++j) {
      int c = wave * 4 + j;                 // A chunk 0..15
      int row = c * 16 + (lane >> 2);
      int pos = lane & 3;
      int g = pos ^ ((row >> 1) & 3);
      gsrc[j] = A + (size_t)(row0 + row) * H_DIM + g * 8;
      ldsoff[j] = c * 1024;
    }
    gsrc[4] = gsrc[0]; ldsoff[4] = ldsoff[0];  // never issued for A-waves
  } else {
#pragma unroll
    for (int j = 0; j < 5; ++j) {
      int c = (wave - 4) * 5 + j;           // B chunk 0..19
      int m = c >> 2;                       // mode (4 chunks per mode)
      int r = (c & 3) * 16 + (lane >> 2);   // row within mode slab (0..63)
      int pos = lane & 3;
      int g = pos ^ ((r >> 1) & 3);
      gsrc[j] = Wt + (size_t)m * O_DIM * H_DIM + (size_t)(col0 + r) * H_DIM + g * 8;
      ldsoff[j] = 16384 + c * 1024;
    }
  }

  // ---- loop-invariant fragment byte offsets (ushort units; row = 32 ushorts)
  int aoffs[4];
#pragma unroll
  for (int t = 0; t < 4; ++t) {
    int ra = wrow + t * 16 + ln;
    aoffs[t] = ra * 32 + (q ^ ((ra >> 1) & 3)) * 8;
  }
  int boffs[2];
  {
    int rb = wcol + ln;      boffs[0] = rb * 32 + (q ^ ((rb >> 1) & 3)) * 8;
    int r1 = wcol + 16 + ln; boffs[1] = r1 * 32 + (q ^ ((r1 >> 1) & 3)) * 8;
  }

  float4v acc[5][4][2];
#pragma unroll
  for (int m = 0; m < 5; ++m)
#pragma unroll
    for (int i = 0; i < 4; ++i)
#pragma unroll
      for (int j = 0; j < 2; ++j)
        acc[m][i][j] = (float4v){0.f, 0.f, 0.f, 0.f};

#define ISSUE_SLOT(boff_)                                                       \
  do {                                                                          \
    unsigned char* _dst = smem + (boff_);                                       \
    __builtin_amdgcn_global_load_lds(                                           \
        (const __attribute__((address_space(1))) void*)gsrc[0],                 \
        (__attribute__((address_space(3))) void*)(_dst + ldsoff[0]), 16, 0, 0); \
    __builtin_amdgcn_global_load_lds(                                           \
        (const __attribute__((address_space(1))) void*)gsrc[1],                 \
        (__attribute__((address_space(3))) void*)(_dst + ldsoff[1]), 16, 0, 0); \
    __builtin_amdgcn_global_load_lds(                                           \
        (const __attribute__((address_space(1))) void*)gsrc[2],                 \
        (__attribute__((address_space(3))) void*)(_dst + ldsoff[2]), 16, 0, 0); \
    __builtin_amdgcn_global_load_lds(                                           \
        (const __attribute__((address_space(1))) void*)gsrc[3],                 \
        (__attribute__((address_space(3))) void*)(_dst + ldsoff[3]), 16, 0, 0); \
    if (wave >= 4)                                                              \
      __builtin_amdgcn_global_load_lds(                                         \
          (const __attribute__((address_space(1))) void*)gsrc[4],               \
          (__attribute__((address_space(3))) void*)(_dst + ldsoff[4]), 16, 0, 0);\
    _Pragma("unroll") for (int _j = 0; _j < 5; ++_j) gsrc[_j] += 32;            \
  } while (0)

#define WAITL                                                                   \
  do { if (wave < 4) asm volatile("s_waitcnt vmcnt(4)" ::: "memory");           \
       else          asm volatile("s_waitcnt vmcnt(5)" ::: "memory"); } while (0)

#define MFMA_MODE(m_, bb0, bb1)                                                 \
  do {                                                                          \
    acc[m_][0][0] = __builtin_amdgcn_mfma_f32_16x16x32_bf16(a0, bb0, acc[m_][0][0], 0, 0, 0); \
    acc[m_][1][0] = __builtin_amdgcn_mfma_f32_16x16x32_bf16(a1, bb0, acc[m_][1][0], 0, 0, 0); \
    acc[m_][2][0] = __builtin_amdgcn_mfma_f32_16x16x32_bf16(a2, bb0, acc[m_][2][0], 0, 0, 0); \
    acc[m_][3][0] = __builtin_amdgcn_mfma_f32_16x16x32_bf16(a3, bb0, acc[m_][3][0], 0, 0, 0); \
    acc[m_][0][1] = __builtin_amdgcn_mfma_f32_16x16x32_bf16(a0, bb1, acc[m_][0][1], 0, 0, 0); \
    acc[m_][1][1] = __builtin_amdgcn_mfma_f32_16x16x32_bf16(a1, bb1, acc[m_][1][1], 0, 0, 0); \
    acc[m_][2][1] = __builtin_amdgcn_mfma_f32_16x16x32_bf16(a2, bb1, acc[m_][2][1], 0, 0, 0); \
    acc[m_][3][1] = __builtin_amdgcn_mfma_f32_16x16x32_bf16(a3, bb1, acc[m_][3][1], 0, 0, 0); \
  } while (0)

// full compute of one landed slot: 14 ds_reads + 40 MFMA.
// A at slot base; B region at ushort offset 8192; mode m at +m*2048 ushorts.
#define COMPUTE_SLOT(boff_)                                                     \
  do {                                                                          \
    const unsigned short* _sA = (const unsigned short*)(smem + (boff_));        \
    const unsigned short* _sB = _sA + 8192;                                     \
    bf16x8 a0 = *(const bf16x8*)(_sA + aoffs[0]);                               \
    bf16x8 a1 = *(const bf16x8*)(_sA + aoffs[1]);                               \
    bf16x8 a2 = *(const bf16x8*)(_sA + aoffs[2]);                               \
    bf16x8 a3 = *(const bf16x8*)(_sA + aoffs[3]);                               \
    bf16x8 b00 = *(const bf16x8*)(_sB + boffs[0]);                              \
    bf16x8 b01 = *(const bf16x8*)(_sB + boffs[1]);                              \
    bf16x8 b10 = *(const bf16x8*)(_sB + 2048 + boffs[0]);                       \
    bf16x8 b11 = *(const bf16x8*)(_sB + 2048 + boffs[1]);                       \
    bf16x8 c20 = *(const bf16x8*)(_sB + 2 * 2048 + boffs[0]);                   \
    bf16x8 c21 = *(const bf16x8*)(_sB + 2 * 2048 + boffs[1]);                   \
    bf16x8 c30 = *(const bf16x8*)(_sB + 3 * 2048 + boffs[0]);                   \
    bf16x8 c31 = *(const bf16x8*)(_sB + 3 * 2048 + boffs[1]);                   \
    bf16x8 c40 = *(const bf16x8*)(_sB + 4 * 2048 + boffs[0]);                   \
    bf16x8 c41 = *(const bf16x8*)(_sB + 4 * 2048 + boffs[1]);                   \
    __builtin_amdgcn_s_setprio(1);                                              \
    MFMA_MODE(0, b00, b01);                                                     \
    MFMA_MODE(1, b10, b11);                                                     \
    MFMA_MODE(2, c20, c21);                                                     \
    MFMA_MODE(3, c30, c31);                                                     \
    MFMA_MODE(4, c40, c41);                                                     \
    __builtin_amdgcn_s_setprio(0);                                              \
  } while (0)

  // ---- prologue: fill slot 0 (stage 0); scf prep overlaps the DMA
  ISSUE_SLOT(0u);
  if (tid < 256) {
    int b = row0 + tid;
    float s = se[b];
    float l0 = fmaf(s, gw[0], gb[0]);
    float l1 = fmaf(s, gw[1], gb[1]);
    float l2 = fmaf(s, gw[2], gb[2]);
    float l3 = fmaf(s, gw[3], gb[3]);
    float mx = fmaxf(fmaxf(l0, l1), fmaxf(l2, l3));
    float e0 = __expf(l0 - mx), e1 = __expf(l1 - mx);
    float e2 = __expf(l2 - mx), e3 = __expf(l3 - mx);
    float mix = 1.0f / (1.0f + __expf(-curv[b]));
    float inv = mix / (e0 + e1 + e2 + e3);
    scf[0 * 256 + tid] = e0 * inv;
    scf[1 * 256 + tid] = e1 * inv;
    scf[2 * 256 + tid] = e2 * inv;
    scf[3 * 256 + tid] = e3 * inv;
    scf[4 * 256 + tid] = 1.0f - mix;
  }
  asm volatile("s_waitcnt lgkmcnt(0)" ::: "memory");  // scf ds_writes retired

  // ---- main loop: stages 0..30 issue next; stage 31 tail
#pragma unroll 1
  for (int s = 0; s < 31; ++s) {
    const unsigned int cur = (unsigned int)(s & 1) * 36864u;
    const unsigned int nxt = (unsigned int)((s + 1) & 1) * 36864u;
    ISSUE_SLOT(nxt);                   // slot freed by barrier B of stage s-1
    WAITL;                             // own DMA(s) landed; DMA(s+1) in flight
    __builtin_amdgcn_s_barrier();      // A: all waves' DMA(s) landed
    __builtin_amdgcn_sched_barrier(0);
    COMPUTE_SLOT(cur);                 // 14 reads + 40 MFMA
    __builtin_amdgcn_s_barrier();      // B: all done reading slot s
  }
  {
    const unsigned int cur = (unsigned int)(31 & 1) * 36864u;
    asm volatile("s_waitcnt vmcnt(0)" ::: "memory");  // DMA(31) landed (tail only)
    __builtin_amdgcn_s_barrier();
    __builtin_amdgcn_sched_barrier(0);
    COMPUTE_SLOT(cur);
  }

  // ---- epilogue: mode-combine -> LDS repack (fp32, pitch 68) -> float4 stores
  __syncthreads();
  float* fbuf = (float*)smem;  // 256 x 68 fp32 = 69632 B (scf at 73728 safe)
#pragma unroll
  for (int ti = 0; ti < 4; ++ti) {
    int rl = wrow + ti * 16 + q * 4;
#pragma unroll
    for (int tj = 0; tj < 2; ++tj) {
      int cc = wcol + tj * 16 + ln;
#pragma unroll
      for (int r = 0; r < 4; ++r) {
        float v = 0.f;
#pragma unroll
        for (int m = 0; m < 5; ++m)
          v += scf[m * 256 + rl + r] * acc[m][ti][tj][r];
        fbuf[(rl + r) * 68 + cc] = v;
      }
    }
  }
  __syncthreads();
#pragma unroll
  for (int i = 0; i < 8; ++i) {
    int L = i * 512 + tid;          // 4096 float4s = 256 rows x 16
    int row = L >> 4, c4 = L & 15;
    float4v v = *(const float4v*)(fbuf + row * 68 + c4 * 4);
    float cb = scf[4 * 256 + row];
    float4v pb = *(const float4v*)(prjb + col0 + c4 * 4);
    v += cb * pb;
    *(float4v*)(out + (size_t)(row0 + row) * O_DIM + col0 + c4 * 4) = v;
  }
#undef ISSUE_SLOT
#undef WAITL
#undef MFMA_MODE
#undef COMPUTE_SLOT
}

// ---------------------------------------------------------------------------
extern "C" void kernel_launch(void* const* d_in, const int* in_sizes, int n_in,
                              void* d_out, int out_size, void* d_ws, size_t ws_size,
                              hipStream_t stream) {
  const float* state = (const float*)d_in[0];
  const float* se    = (const float*)d_in[1];
  const float* curv  = (const float*)d_in[2];
  const float* basis = (const float*)d_in[3];
  const float* gw    = (const float*)d_in[4];
  const float* gb    = (const float*)d_in[5];
  const float* prjw  = (const float*)d_in[6];
  const float* prjb  = (const float*)d_in[7];
  float* out = (float*)d_out;

  char* ws = (char*)d_ws;
  unsigned short* Abf = (unsigned short*)ws;                               // 16 MB
  unsigned short* Wt  = (unsigned short*)(ws + (size_t)16 * 1024 * 1024);  // 10 MB

  prep_inputs<<<5376, 256, 0, stream>>>(state, basis, prjw, Abf, Wt);
  dim3 gg(B_DIM / 256, O_DIM / 64);
  gemm_fused<<<gg, 512, 0, stream>>>(Abf, Wt, se, curv, gw, gb, prjb, out);
}

// Round 11
// 298.286 us; speedup vs baseline: 3.6752x; 3.6752x over previous
//
#include <hip/hip_runtime.h>
#include <stdint.h>

typedef __attribute__((ext_vector_type(4))) float  float4v;
typedef __attribute__((ext_vector_type(8))) __bf16 bf16x8;
typedef __attribute__((ext_vector_type(8))) unsigned short ushort8;

#define B_DIM 8192
#define H_DIM 1024
#define O_DIM 1024

static __device__ __forceinline__ unsigned short f32_to_bf16(float f) {
  union { float f; unsigned int u; } v; v.f = f;
  unsigned int u = v.u;
  unsigned int r = u + 0x7FFFu + ((u >> 16) & 1u);  // round-to-nearest-even
  return (unsigned short)(r >> 16);
}

// ---------------------------------------------------------------------------
// prep_inputs: unchanged (near memory floor).
// ---------------------------------------------------------------------------
__global__ void prep_inputs(const float* __restrict__ state,
                            const float* __restrict__ basis,
                            const float* __restrict__ prjw,
                            unsigned short* __restrict__ Abf,
                            unsigned short* __restrict__ Wt) {
  __shared__ __align__(16) unsigned short t[64 * 72];
  int bb = blockIdx.x;
  int tid = threadIdx.x;
  if (bb < 1280) {
    int m = bb >> 8, panel = bb & 255;
    int o0 = (panel & 15) * 64, h0 = (panel >> 4) * 64;
    const float* src = (m < 4) ? (basis + (size_t)m * H_DIM * O_DIM) : prjw;  // [H][O]
    int r  = tid >> 4;
    int c4 = (tid & 15) * 4;
#pragma unroll
    for (int p = 0; p < 4; ++p) {
      int h = r + p * 16;
      float4v v = *(const float4v*)(src + (size_t)(h0 + h) * O_DIM + o0 + c4);
      t[(c4 + 0) * 72 + h] = f32_to_bf16(v.x);
      t[(c4 + 1) * 72 + h] = f32_to_bf16(v.y);
      t[(c4 + 2) * 72 + h] = f32_to_bf16(v.z);
      t[(c4 + 3) * 72 + h] = f32_to_bf16(v.w);
    }
    __syncthreads();
#pragma unroll
    for (int i = 0; i < 2; ++i) {
      int C = i * 256 + tid;
      int o = C >> 3, cc = C & 7;
      ushort8 val = *(const ushort8*)(t + o * 72 + cc * 8);
      *(ushort8*)(Wt + ((size_t)m * O_DIM + o0 + o) * H_DIM + h0 + cc * 8) = val;
    }
  } else {
    int i = (bb - 1280) * 256 + tid;  // 8 elems per thread
    float4v v0 = ((const float4v*)state)[i * 2];
    float4v v1 = ((const float4v*)state)[i * 2 + 1];
    ushort8 o;
    o[0] = f32_to_bf16(v0.x); o[1] = f32_to_bf16(v0.y);
    o[2] = f32_to_bf16(v0.z); o[3] = f32_to_bf16(v0.w);
    o[4] = f32_to_bf16(v1.x); o[5] = f32_to_bf16(v1.y);
    o[6] = f32_to_bf16(v1.z); o[7] = f32_to_bf16(v1.w);
    ((ushort8*)Abf)[i] = o;
  }
}

// ---------------------------------------------------------------------------
// R11: B direct-to-register, A stays DMA->LDS (3-slot ring, counted vmcnt).
//  Diagnosis: LDS pipe (~2000 cyc/CU-stage: 112 b128 reads + 57KB DMA writes)
//  exceeds matrix (1552) and serializes at 2-waves/SIMD lockstep (occupancy
//  is hard-capped by the 160-reg accumulator — R10 proved buying more waves
//  just spills).  B is 80/112 reads + 40KB/57KB writes AND has perfect L2
//  locality (x-fastest grid -> 8 XCD-mates share one 640KB col-panel < 4MB
//  L2).  So: B frags load straight to registers (pB mapping verified in R6;
//  NO double-buffer — that was R6's spill), A keeps the verified ring.
//  LDS pipe drops to ~580 cyc << matrix.
//  FIFO ledger/stage: [Bglob(s) x10, ISSUE_A(s+2) x2]; last B-frag use needs
//  vmcnt(2) only -> A prefetch never drained; WAITL=vmcnt(2) certifies
//  A(s+1) before the single barrier.  Uniform duty: 2 A-chunks/wave.
// ---------------------------------------------------------------------------
__global__ __launch_bounds__(512, 2)
void gemm_fused(const unsigned short* __restrict__ A,
                const unsigned short* __restrict__ Wt,
                const float* __restrict__ se, const float* __restrict__ curv,
                const float* __restrict__ gw, const float* __restrict__ gb,
                const float* __restrict__ prjb,
                float* __restrict__ out) {
  __shared__ __align__(16) unsigned char smem[54272];  // 3*16384 + 5120 (scf)
  float* scf = (float*)(smem + 49152);  // 5 x 256 fp32 = 5120 B

  const int tid  = threadIdx.x;
  const int lane = tid & 63;
  const int wave = tid >> 6;
  const int row0 = blockIdx.x * 256;
  const int col0 = blockIdx.y * 64;
  const int wrow = (wave >> 1) * 64;   // 0,64,128,192
  const int wcol = (wave & 1) * 32;    // 0 or 32
  const int q  = lane >> 4;
  const int ln = lane & 15;

  // ---- A staging: 16 chunks (1KB = 16 rows x 32k), 2 per wave, all waves.
  const unsigned short* gsrc[2];
  unsigned int ldsoff[2];
#pragma unroll
  for (int j = 0; j < 2; ++j) {
    int c = wave * 2 + j;                 // A chunk 0..15
    int row = c * 16 + (lane >> 2);
    int pos = lane & 3;
    int g = pos ^ ((row >> 1) & 3);
    gsrc[j] = A + (size_t)(row0 + row) * H_DIM + g * 8;
    ldsoff[j] = c * 1024;
  }

  // ---- A fragment ds_read offsets (ushort units; row = 32 ushorts)
  int aoffs[4];
#pragma unroll
  for (int t = 0; t < 4; ++t) {
    int ra = wrow + t * 16 + ln;
    aoffs[t] = ra * 32 + (q ^ ((ra >> 1) & 3)) * 8;
  }

  // ---- B direct per-lane pointers (mapping verified correct in R6 run)
  const unsigned short* pB[5][2];
#pragma unroll
  for (int m = 0; m < 5; ++m)
#pragma unroll
    for (int j = 0; j < 2; ++j)
      pB[m][j] = Wt + (size_t)m * O_DIM * H_DIM +
                 (size_t)(col0 + wcol + 16 * j + ln) * H_DIM + 8 * q;

  float4v acc[5][4][2];
#pragma unroll
  for (int m = 0; m < 5; ++m)
#pragma unroll
    for (int i = 0; i < 4; ++i)
#pragma unroll
      for (int j = 0; j < 2; ++j)
        acc[m][i][j] = (float4v){0.f, 0.f, 0.f, 0.f};

#define ISSUE_A(boff_)                                                          \
  do {                                                                          \
    unsigned char* _dst = smem + (boff_);                                       \
    __builtin_amdgcn_global_load_lds(                                           \
        (const __attribute__((address_space(1))) void*)gsrc[0],                 \
        (__attribute__((address_space(3))) void*)(_dst + ldsoff[0]), 16, 0, 0); \
    __builtin_amdgcn_global_load_lds(                                           \
        (const __attribute__((address_space(1))) void*)gsrc[1],                 \
        (__attribute__((address_space(3))) void*)(_dst + ldsoff[1]), 16, 0, 0); \
    gsrc[0] += 32; gsrc[1] += 32;                                               \
  } while (0)

#define MFMA_MODE(m_, bb0, bb1)                                                 \
  do {                                                                          \
    acc[m_][0][0] = __builtin_amdgcn_mfma_f32_16x16x32_bf16(a0, bb0, acc[m_][0][0], 0, 0, 0); \
    acc[m_][1][0] = __builtin_amdgcn_mfma_f32_16x16x32_bf16(a1, bb0, acc[m_][1][0], 0, 0, 0); \
    acc[m_][2][0] = __builtin_amdgcn_mfma_f32_16x16x32_bf16(a2, bb0, acc[m_][2][0], 0, 0, 0); \
    acc[m_][3][0] = __builtin_amdgcn_mfma_f32_16x16x32_bf16(a3, bb0, acc[m_][3][0], 0, 0, 0); \
    acc[m_][0][1] = __builtin_amdgcn_mfma_f32_16x16x32_bf16(a0, bb1, acc[m_][0][1], 0, 0, 0); \
    acc[m_][1][1] = __builtin_amdgcn_mfma_f32_16x16x32_bf16(a1, bb1, acc[m_][1][1], 0, 0, 0); \
    acc[m_][2][1] = __builtin_amdgcn_mfma_f32_16x16x32_bf16(a2, bb1, acc[m_][2][1], 0, 0, 0); \
    acc[m_][3][1] = __builtin_amdgcn_mfma_f32_16x16x32_bf16(a3, bb1, acc[m_][3][1], 0, 0, 0); \
  } while (0)

// One stage: 10 B global loads (koff), 4 A ds_reads (slot), 40 MFMA.
// Source order: B-globals FIRST, then ISSUE_A -> last B-frag needs vmcnt(2).
#define STAGE_BODY(slotoff_, koff_, DO_ISSUE, issoff_)                          \
  do {                                                                          \
    bf16x8 b00 = *(const bf16x8*)(pB[0][0] + (koff_));                          \
    bf16x8 b01 = *(const bf16x8*)(pB[0][1] + (koff_));                          \
    bf16x8 b10 = *(const bf16x8*)(pB[1][0] + (koff_));                          \
    bf16x8 b11 = *(const bf16x8*)(pB[1][1] + (koff_));                          \
    bf16x8 c20 = *(const bf16x8*)(pB[2][0] + (koff_));                          \
    bf16x8 c21 = *(const bf16x8*)(pB[2][1] + (koff_));                          \
    bf16x8 c30 = *(const bf16x8*)(pB[3][0] + (koff_));                          \
    bf16x8 c31 = *(const bf16x8*)(pB[3][1] + (koff_));                          \
    bf16x8 c40 = *(const bf16x8*)(pB[4][0] + (koff_));                          \
    bf16x8 c41 = *(const bf16x8*)(pB[4][1] + (koff_));                          \
    if (DO_ISSUE) ISSUE_A(issoff_);                                             \
    const unsigned short* _sA = (const unsigned short*)(smem + (slotoff_));     \
    bf16x8 a0 = *(const bf16x8*)(_sA + aoffs[0]);                               \
    bf16x8 a1 = *(const bf16x8*)(_sA + aoffs[1]);                               \
    bf16x8 a2 = *(const bf16x8*)(_sA + aoffs[2]);                               \
    bf16x8 a3 = *(const bf16x8*)(_sA + aoffs[3]);                               \
    __builtin_amdgcn_s_setprio(1);                                              \
    MFMA_MODE(0, b00, b01);                                                     \
    MFMA_MODE(1, b10, b11);                                                     \
    MFMA_MODE(2, c20, c21);                                                     \
    MFMA_MODE(3, c30, c31);                                                     \
    MFMA_MODE(4, c40, c41);                                                     \
    __builtin_amdgcn_s_setprio(0);                                              \
  } while (0)

  // ---- prologue: fill A slots 0,1 (stages 0,1); scf prep overlaps DMA
  ISSUE_A(0u);
  ISSUE_A(16384u);
  if (tid < 256) {
    int b = row0 + tid;
    float s = se[b];
    float l0 = fmaf(s, gw[0], gb[0]);
    float l1 = fmaf(s, gw[1], gb[1]);
    float l2 = fmaf(s, gw[2], gb[2]);
    float l3 = fmaf(s, gw[3], gb[3]);
    float mx = fmaxf(fmaxf(l0, l1), fmaxf(l2, l3));
    float e0 = __expf(l0 - mx), e1 = __expf(l1 - mx);
    float e2 = __expf(l2 - mx), e3 = __expf(l3 - mx);
    float mix = 1.0f / (1.0f + __expf(-curv[b]));
    float inv = mix / (e0 + e1 + e2 + e3);
    scf[0 * 256 + tid] = e0 * inv;
    scf[1 * 256 + tid] = e1 * inv;
    scf[2 * 256 + tid] = e2 * inv;
    scf[3 * 256 + tid] = e3 * inv;
    scf[4 * 256 + tid] = 1.0f - mix;
  }
  asm volatile("s_waitcnt lgkmcnt(0)" ::: "memory");  // scf ds_writes retired
  asm volatile("s_waitcnt vmcnt(2)" ::: "memory");    // A(0) landed; A(1) in flight
  __builtin_amdgcn_s_barrier();                       // all waves: slot 0 ready

  // ---- main loop: stages 0..29 uniform; tail 30 (no issue), 31
  unsigned int cS = 0u, nS = 16384u, iS = 32768u;
  int kk = 0;
#pragma unroll 1
  for (int s = 0; s < 30; ++s) {
    STAGE_BODY(cS, kk, 1, iS);         // B(s) globals, issue A(s+2), MFMA
    asm volatile("s_waitcnt vmcnt(2)" ::: "memory");  // A(s+1) landed (own wave)
    __builtin_amdgcn_s_barrier();      // all waves: slot s+1 ready; slot s free
    kk += 32;
    unsigned int t_ = cS; cS = nS; nS = iS; iS = t_;
  }
  {
    STAGE_BODY(cS, kk, 0, 0u);         // stage 30
    asm volatile("s_waitcnt vmcnt(0)" ::: "memory");  // A(31) landed
    __builtin_amdgcn_s_barrier();
    kk += 32;
  }
  STAGE_BODY(nS, kk, 0, 0u);           // stage 31

  // ---- epilogue: mode-combine -> LDS repack (fp32, pitch 68) -> float4 stores
  __syncthreads();
  float* fbuf = (float*)smem;  // 256 x 68 fp32 = 69632 B... exceeds 54272!
  // NOTE: repack in two half-passes of 128 rows to stay inside 54272 B.
#pragma unroll
  for (int half = 0; half < 2; ++half) {
    // rows [half*128, half*128+128): only waves whose wrow is in this half
    if ((wrow >> 7) == half) {
#pragma unroll
      for (int ti = 0; ti < 4; ++ti) {
        int rl = (wrow & 63) + ((wrow >> 6) & 1) * 64 + ti * 16 + q * 4;  // wrow%128 + ...
        int rglob = wrow + ti * 16 + q * 4;
        int rloc = rglob - half * 128;
#pragma unroll
        for (int tj = 0; tj < 2; ++tj) {
          int cc = wcol + tj * 16 + ln;
#pragma unroll
          for (int r = 0; r < 4; ++r) {
            float v = 0.f;
#pragma unroll
            for (int m = 0; m < 5; ++m)
              v += scf[m * 256 + rglob + r] * acc[m][ti][tj][r];
            fbuf[(rloc + r) * 68 + cc] = v;
          }
        }
      }
    }
    __syncthreads();
    // all 512 threads store this half's 128 rows x 16 float4s = 2048
#pragma unroll
    for (int i = 0; i < 4; ++i) {
      int L = i * 512 + tid;          // 2048 float4s
      int row = L >> 4, c4 = L & 15;
      float4v v = *(const float4v*)(fbuf + row * 68 + c4 * 4);
      float cb = scf[4 * 256 + half * 128 + row];
      float4v pb = *(const float4v*)(prjb + col0 + c4 * 4);
      v += cb * pb;
      *(float4v*)(out + (size_t)(row0 + half * 128 + row) * O_DIM + col0 + c4 * 4) = v;
    }
    __syncthreads();
  }
#undef ISSUE_A
#undef MFMA_MODE
#undef STAGE_BODY
}

// ---------------------------------------------------------------------------
extern "C" void kernel_launch(void* const* d_in, const int* in_sizes, int n_in,
                              void* d_out, int out_size, void* d_ws, size_t ws_size,
                              hipStream_t stream) {
  const float* state = (const float*)d_in[0];
  const float* se    = (const float*)d_in[1];
  const float* curv  = (const float*)d_in[2];
  const float* basis = (const float*)d_in[3];
  const float* gw    = (const float*)d_in[4];
  const float* gb    = (const float*)d_in[5];
  const float* prjw  = (const float*)d_in[6];
  const float* prjb  = (const float*)d_in[7];
  float* out = (float*)d_out;

  char* ws = (char*)d_ws;
  unsigned short* Abf = (unsigned short*)ws;                               // 16 MB
  unsigned short* Wt  = (unsigned short*)(ws + (size_t)16 * 1024 * 1024);  // 10 MB

  prep_inputs<<<5376, 256, 0, stream>>>(state, basis, prjw, Abf, Wt);
  dim3 gg(B_DIM / 256, O_DIM / 64);
  gemm_fused<<<gg, 512, 0, stream>>>(Abf, Wt, se, curv, gw, gb, prjb, out);
}

// Round 12
// 180.707 us; speedup vs baseline: 6.0666x; 1.6507x over previous
//
#include <hip/hip_runtime.h>
#include <stdint.h>

typedef __attribute__((ext_vector_type(4))) float  float4v;
typedef __attribute__((ext_vector_type(8))) __bf16 bf16x8;
typedef __attribute__((ext_vector_type(8))) unsigned short ushort8;

#define B_DIM 8192
#define H_DIM 1024
#define O_DIM 1024

static __device__ __forceinline__ unsigned short f32_to_bf16(float f) {
  union { float f; unsigned int u; } v; v.f = f;
  unsigned int u = v.u;
  unsigned int r = u + 0x7FFFu + ((u >> 16) & 1u);  // round-to-nearest-even
  return (unsigned short)(r >> 16);
}

// ---------------------------------------------------------------------------
// prep_inputs: unchanged (near memory floor).
// ---------------------------------------------------------------------------
__global__ void prep_inputs(const float* __restrict__ state,
                            const float* __restrict__ basis,
                            const float* __restrict__ prjw,
                            unsigned short* __restrict__ Abf,
                            unsigned short* __restrict__ Wt) {
  __shared__ __align__(16) unsigned short t[64 * 72];
  int bb = blockIdx.x;
  int tid = threadIdx.x;
  if (bb < 1280) {
    int m = bb >> 8, panel = bb & 255;
    int o0 = (panel & 15) * 64, h0 = (panel >> 4) * 64;
    const float* src = (m < 4) ? (basis + (size_t)m * H_DIM * O_DIM) : prjw;  // [H][O]
    int r  = tid >> 4;
    int c4 = (tid & 15) * 4;
#pragma unroll
    for (int p = 0; p < 4; ++p) {
      int h = r + p * 16;
      float4v v = *(const float4v*)(src + (size_t)(h0 + h) * O_DIM + o0 + c4);
      t[(c4 + 0) * 72 + h] = f32_to_bf16(v.x);
      t[(c4 + 1) * 72 + h] = f32_to_bf16(v.y);
      t[(c4 + 2) * 72 + h] = f32_to_bf16(v.z);
      t[(c4 + 3) * 72 + h] = f32_to_bf16(v.w);
    }
    __syncthreads();
#pragma unroll
    for (int i = 0; i < 2; ++i) {
      int C = i * 256 + tid;
      int o = C >> 3, cc = C & 7;
      ushort8 val = *(const ushort8*)(t + o * 72 + cc * 8);
      *(ushort8*)(Wt + ((size_t)m * O_DIM + o0 + o) * H_DIM + h0 + cc * 8) = val;
    }
  } else {
    int i = (bb - 1280) * 256 + tid;  // 8 elems per thread
    float4v v0 = ((const float4v*)state)[i * 2];
    float4v v1 = ((const float4v*)state)[i * 2 + 1];
    ushort8 o;
    o[0] = f32_to_bf16(v0.x); o[1] = f32_to_bf16(v0.y);
    o[2] = f32_to_bf16(v0.z); o[3] = f32_to_bf16(v0.w);
    o[4] = f32_to_bf16(v1.x); o[5] = f32_to_bf16(v1.y);
    o[6] = f32_to_bf16(v1.z); o[7] = f32_to_bf16(v1.w);
    ((ushort8*)Abf)[i] = o;
  }
}

// ---------------------------------------------------------------------------
// R12 = R9 (verified 82us) + T19 sched_group_barrier interleave.
//  Theory: R9 clumps 14 ds_reads then 40 MFMAs -> LDS burst and matrix burst
//  serialize (sum-regime, MfmaUtil 45%).  m201 hits 62% at the same
//  waves/SIMD by fine interleave.  Pin emission per stage:
//    MFMA8(m0,carried) -> DS2(c2) -> MFMA8(m1,carried) -> DS2(c3) ->
//    MFMA8(m2) -> DS2(c4) -> MFMA16(m3,m4)
//  Each DS pair's latency hides under the preceding ~155-cyc MFMA cluster;
//  only READ_PH0's 8 post-barrier reads stay exposed.
//  Everything else byte-identical to R9 (3-slot ring, counted vmcnt(L),
//  one s_barrier/stage, carried ph0 frags, verified offsets).
// ---------------------------------------------------------------------------
__global__ __launch_bounds__(512, 2)
void gemm_fused(const unsigned short* __restrict__ A,
                const unsigned short* __restrict__ Wt,
                const float* __restrict__ se, const float* __restrict__ curv,
                const float* __restrict__ gw, const float* __restrict__ gb,
                const float* __restrict__ prjb,
                float* __restrict__ out) {
  __shared__ __align__(16) unsigned char smem[115712];  // 3*36864 + 5120 (scf)
  float* scf = (float*)(smem + 110592);  // 5 x 256 fp32 = 5120 B

  const int tid  = threadIdx.x;
  const int lane = tid & 63;
  const int wave = tid >> 6;
  const int row0 = blockIdx.x * 256;
  const int col0 = blockIdx.y * 64;
  const int wrow = (wave >> 1) * 64;   // 0,64,128,192
  const int wcol = (wave & 1) * 32;    // 0 or 32
  const int q  = lane >> 4;
  const int ln = lane & 15;

  // ---- staging descriptors.  1KB wave-chunk = 16 rows x 32k bf16.
  const unsigned short* gsrc[5];
  unsigned int ldsoff[5];
  if (wave < 4) {
#pragma unroll
    for (int j = 0; j < 4; ++j) {
      int c = wave * 4 + j;                 // A chunk 0..15
      int row = c * 16 + (lane >> 2);
      int pos = lane & 3;
      int g = pos ^ ((row >> 1) & 3);
      gsrc[j] = A + (size_t)(row0 + row) * H_DIM + g * 8;
      ldsoff[j] = c * 1024;
    }
    gsrc[4] = gsrc[0]; ldsoff[4] = ldsoff[0];  // never issued for A-waves
  } else {
#pragma unroll
    for (int j = 0; j < 5; ++j) {
      int c = (wave - 4) * 5 + j;           // B chunk 0..19
      int m = c >> 2;                       // mode (4 chunks per mode)
      int r = (c & 3) * 16 + (lane >> 2);   // row within mode slab (0..63)
      int pos = lane & 3;
      int g = pos ^ ((r >> 1) & 3);
      gsrc[j] = Wt + (size_t)m * O_DIM * H_DIM + (size_t)(col0 + r) * H_DIM + g * 8;
      ldsoff[j] = 16384 + c * 1024;
    }
  }

  // ---- loop-invariant fragment byte offsets (ushort units; row = 32 ushorts)
  int aoffs[4];
#pragma unroll
  for (int t = 0; t < 4; ++t) {
    int ra = wrow + t * 16 + ln;
    aoffs[t] = ra * 32 + (q ^ ((ra >> 1) & 3)) * 8;
  }
  int boffs[2];
  {
    int rb = wcol + ln;      boffs[0] = rb * 32 + (q ^ ((rb >> 1) & 3)) * 8;
    int r1 = wcol + 16 + ln; boffs[1] = r1 * 32 + (q ^ ((r1 >> 1) & 3)) * 8;
  }

  float4v acc[5][4][2];
#pragma unroll
  for (int m = 0; m < 5; ++m)
#pragma unroll
    for (int i = 0; i < 4; ++i)
#pragma unroll
      for (int j = 0; j < 2; ++j)
        acc[m][i][j] = (float4v){0.f, 0.f, 0.f, 0.f};

#define ISSUE_SLOT(boff_)                                                       \
  do {                                                                          \
    unsigned char* _dst = smem + (boff_);                                       \
    __builtin_amdgcn_global_load_lds(                                           \
        (const __attribute__((address_space(1))) void*)gsrc[0],                 \
        (__attribute__((address_space(3))) void*)(_dst + ldsoff[0]), 16, 0, 0); \
    __builtin_amdgcn_global_load_lds(                                           \
        (const __attribute__((address_space(1))) void*)gsrc[1],                 \
        (__attribute__((address_space(3))) void*)(_dst + ldsoff[1]), 16, 0, 0); \
    __builtin_amdgcn_global_load_lds(                                           \
        (const __attribute__((address_space(1))) void*)gsrc[2],                 \
        (__attribute__((address_space(3))) void*)(_dst + ldsoff[2]), 16, 0, 0); \
    __builtin_amdgcn_global_load_lds(                                           \
        (const __attribute__((address_space(1))) void*)gsrc[3],                 \
        (__attribute__((address_space(3))) void*)(_dst + ldsoff[3]), 16, 0, 0); \
    if (wave >= 4)                                                              \
      __builtin_amdgcn_global_load_lds(                                         \
          (const __attribute__((address_space(1))) void*)gsrc[4],               \
          (__attribute__((address_space(3))) void*)(_dst + ldsoff[4]), 16, 0, 0);\
    _Pragma("unroll") for (int _j = 0; _j < 5; ++_j) gsrc[_j] += 32;            \
  } while (0)

#define WAITL                                                                   \
  do { if (wave < 4) asm volatile("s_waitcnt vmcnt(4)" ::: "memory");           \
       else          asm volatile("s_waitcnt vmcnt(5)" ::: "memory"); } while (0)

  // persistent ph0 fragments (carried across the barrier)
  bf16x8 a0, a1, a2, a3, b00, b01, b10, b11;

#define READ_PH0(boff_)                                                         \
  do {                                                                          \
    const unsigned short* _sA = (const unsigned short*)(smem + (boff_));        \
    const unsigned short* _sB = _sA + 8192;                                     \
    a0 = *(const bf16x8*)(_sA + aoffs[0]);                                      \
    a1 = *(const bf16x8*)(_sA + aoffs[1]);                                      \
    a2 = *(const bf16x8*)(_sA + aoffs[2]);                                      \
    a3 = *(const bf16x8*)(_sA + aoffs[3]);                                      \
    b00 = *(const bf16x8*)(_sB + boffs[0]);                                     \
    b01 = *(const bf16x8*)(_sB + boffs[1]);                                     \
    b10 = *(const bf16x8*)(_sB + 2048 + boffs[0]);                              \
    b11 = *(const bf16x8*)(_sB + 2048 + boffs[1]);                              \
  } while (0)

#define MFMA_MODE(m_, bb0, bb1)                                                 \
  do {                                                                          \
    acc[m_][0][0] = __builtin_amdgcn_mfma_f32_16x16x32_bf16(a0, bb0, acc[m_][0][0], 0, 0, 0); \
    acc[m_][1][0] = __builtin_amdgcn_mfma_f32_16x16x32_bf16(a1, bb0, acc[m_][1][0], 0, 0, 0); \
    acc[m_][2][0] = __builtin_amdgcn_mfma_f32_16x16x32_bf16(a2, bb0, acc[m_][2][0], 0, 0, 0); \
    acc[m_][3][0] = __builtin_amdgcn_mfma_f32_16x16x32_bf16(a3, bb0, acc[m_][3][0], 0, 0, 0); \
    acc[m_][0][1] = __builtin_amdgcn_mfma_f32_16x16x32_bf16(a0, bb1, acc[m_][0][1], 0, 0, 0); \
    acc[m_][1][1] = __builtin_amdgcn_mfma_f32_16x16x32_bf16(a1, bb1, acc[m_][1][1], 0, 0, 0); \
    acc[m_][2][1] = __builtin_amdgcn_mfma_f32_16x16x32_bf16(a2, bb1, acc[m_][2][1], 0, 0, 0); \
    acc[m_][3][1] = __builtin_amdgcn_mfma_f32_16x16x32_bf16(a3, bb1, acc[m_][3][1], 0, 0, 0); \
  } while (0)

// B region of a slot = ushort offset 8192 (byte 16384).  Mode m at +m*2048.
#define PH1_READS(boff_)                                                        \
  const unsigned short* _cB = (const unsigned short*)(smem + (boff_)) + 8192;   \
  bf16x8 c20 = *(const bf16x8*)(_cB + 2 * 2048 + boffs[0]);                     \
  bf16x8 c21 = *(const bf16x8*)(_cB + 2 * 2048 + boffs[1]);                     \
  bf16x8 c30 = *(const bf16x8*)(_cB + 3 * 2048 + boffs[0]);                     \
  bf16x8 c31 = *(const bf16x8*)(_cB + 3 * 2048 + boffs[1]);                     \
  bf16x8 c40 = *(const bf16x8*)(_cB + 4 * 2048 + boffs[0]);                     \
  bf16x8 c41 = *(const bf16x8*)(_cB + 4 * 2048 + boffs[1])

#define MFMA_ALL5                                                               \
  do {                                                                          \
    __builtin_amdgcn_s_setprio(1);                                              \
    MFMA_MODE(0, b00, b01);                                                     \
    MFMA_MODE(1, b10, b11);                                                     \
    MFMA_MODE(2, c20, c21);                                                     \
    MFMA_MODE(3, c30, c31);                                                     \
    MFMA_MODE(4, c40, c41);                                                     \
    __builtin_amdgcn_s_setprio(0);                                              \
  } while (0)

// T19: prescribe per-stage emission: carried-MFMA clusters cover the
// just-in-time B reads.  Masks: MFMA=0x8, DS_READ=0x100.
#define SGB_INTERLEAVE                                                          \
  do {                                                                          \
    __builtin_amdgcn_sched_group_barrier(0x008, 8, 0);   /* m0 (carried) */     \
    __builtin_amdgcn_sched_group_barrier(0x100, 2, 0);   /* c2 reads     */     \
    __builtin_amdgcn_sched_group_barrier(0x008, 8, 0);   /* m1 (carried) */     \
    __builtin_amdgcn_sched_group_barrier(0x100, 2, 0);   /* c3 reads     */     \
    __builtin_amdgcn_sched_group_barrier(0x008, 8, 0);   /* m2           */     \
    __builtin_amdgcn_sched_group_barrier(0x100, 2, 0);   /* c4 reads     */     \
    __builtin_amdgcn_sched_group_barrier(0x008, 16, 0);  /* m3 + m4      */     \
  } while (0)

  // ---- prologue: fill slots 0,1 (stages 0,1); scf prep overlaps DMA
  ISSUE_SLOT(0u);
  ISSUE_SLOT(36864u);
  if (tid < 256) {
    int b = row0 + tid;
    float s = se[b];
    float l0 = fmaf(s, gw[0], gb[0]);
    float l1 = fmaf(s, gw[1], gb[1]);
    float l2 = fmaf(s, gw[2], gb[2]);
    float l3 = fmaf(s, gw[3], gb[3]);
    float mx = fmaxf(fmaxf(l0, l1), fmaxf(l2, l3));
    float e0 = __expf(l0 - mx), e1 = __expf(l1 - mx);
    float e2 = __expf(l2 - mx), e3 = __expf(l3 - mx);
    float mix = 1.0f / (1.0f + __expf(-curv[b]));
    float inv = mix / (e0 + e1 + e2 + e3);
    scf[0 * 256 + tid] = e0 * inv;
    scf[1 * 256 + tid] = e1 * inv;
    scf[2 * 256 + tid] = e2 * inv;
    scf[3 * 256 + tid] = e3 * inv;
    scf[4 * 256 + tid] = 1.0f - mix;
  }
  WAITL;                               // stage 0 landed (own wave); stage 1 in flight
  __builtin_amdgcn_s_barrier();        // all waves: stage 0 ready
  __builtin_amdgcn_sched_barrier(0);
  READ_PH0(0u);

  // ---- main loop: stages 0..29 (uniform body), tail 30,31
  unsigned int cS = 0u, nS = 36864u, iS = 73728u;
#pragma unroll 1
  for (int s = 0; s < 30; ++s) {
    ISSUE_SLOT(iS);                    // stage s+2 into the freed slot
    PH1_READS(cS);                     // modes 2-4 frags of stage s
    MFMA_ALL5;                         // ph0 carried + ph1 (counted lgkmcnt)
    SGB_INTERLEAVE;                    // pin {MFMA8,DS2}x3 + MFMA16
    WAITL;                             // stage s+1 landed (own wave); s+2 in flight
    __builtin_amdgcn_s_barrier();      // all waves: stage s+1 ready
    __builtin_amdgcn_sched_barrier(0);
    READ_PH0(nS);                      // ph0 frags of stage s+1
    unsigned int t_ = cS; cS = nS; nS = iS; iS = t_;
  }
  // tail: stage 30 (no issue; drain for stage 31), stage 31
  {
    PH1_READS(cS);
    MFMA_ALL5;
    SGB_INTERLEAVE;
    asm volatile("s_waitcnt vmcnt(0)" ::: "memory");  // stage 31 landed
    __builtin_amdgcn_s_barrier();
    __builtin_amdgcn_sched_barrier(0);
    READ_PH0(nS);
  }
  {
    PH1_READS(nS);
    MFMA_ALL5;
    SGB_INTERLEAVE;
  }

  // ---- epilogue: mode-combine -> LDS repack (fp32, pitch 68) -> float4 stores
  __syncthreads();
  float* fbuf = (float*)smem;  // 256 x 68 fp32 = 69632 B (scf at 110592 safe)
#pragma unroll
  for (int ti = 0; ti < 4; ++ti) {
    int rl = wrow + ti * 16 + q * 4;
#pragma unroll
    for (int tj = 0; tj < 2; ++tj) {
      int cc = wcol + tj * 16 + ln;
#pragma unroll
      for (int r = 0; r < 4; ++r) {
        float v = 0.f;
#pragma unroll
        for (int m = 0; m < 5; ++m)
          v += scf[m * 256 + rl + r] * acc[m][ti][tj][r];
        fbuf[(rl + r) * 68 + cc] = v;
      }
    }
  }
  __syncthreads();
#pragma unroll
  for (int i = 0; i < 8; ++i) {
    int L = i * 512 + tid;          // 4096 float4s = 256 rows x 16
    int row = L >> 4, c4 = L & 15;
    float4v v = *(const float4v*)(fbuf + row * 68 + c4 * 4);
    float cb = scf[4 * 256 + row];
    float4v pb = *(const float4v*)(prjb + col0 + c4 * 4);
    v += cb * pb;
    *(float4v*)(out + (size_t)(row0 + row) * O_DIM + col0 + c4 * 4) = v;
  }
#undef ISSUE_SLOT
#undef WAITL
#undef READ_PH0
#undef MFMA_MODE
#undef PH1_READS
#undef MFMA_ALL5
#undef SGB_INTERLEAVE
}

// ---------------------------------------------------------------------------
extern "C" void kernel_launch(void* const* d_in, const int* in_sizes, int n_in,
                              void* d_out, int out_size, void* d_ws, size_t ws_size,
                              hipStream_t stream) {
  const float* state = (const float*)d_in[0];
  const float* se    = (const float*)d_in[1];
  const float* curv  = (const float*)d_in[2];
  const float* basis = (const float*)d_in[3];
  const float* gw    = (const float*)d_in[4];
  const float* gb    = (const float*)d_in[5];
  const float* prjw  = (const float*)d_in[6];
  const float* prjb  = (const float*)d_in[7];
  float* out = (float*)d_out;

  char* ws = (char*)d_ws;
  unsigned short* Abf = (unsigned short*)ws;                               // 16 MB
  unsigned short* Wt  = (unsigned short*)(ws + (size_t)16 * 1024 * 1024);  // 10 MB

  prep_inputs<<<5376, 256, 0, stream>>>(state, basis, prjw, Abf, Wt);
  dim3 gg(B_DIM / 256, O_DIM / 64);
  gemm_fused<<<gg, 512, 0, stream>>>(Abf, Wt, se, curv, gw, gb, prjb, out);
}